// Round 3
// baseline (234.234 us; speedup 1.0000x reference)
//
#include <hip/hip_runtime.h>
#include <hip/hip_fp16.h>
#include <math.h>

typedef _Float16 half8 __attribute__((ext_vector_type(8)));
typedef float floatx4 __attribute__((ext_vector_type(4)));

#define BB 32
#define SS 48
#define LL 64
#define FF 256

// ---- prep (proven): W1 -> fp16 hi/lo MFMA-B fragment order ----
//   flat = ((kt*16 + nt)*64 + lane)*8 + j ; element = W1[kt*32+(lane>>4)*8+j][nt*16+(lane&15)]
__global__ __launch_bounds__(256) void prep_w(const float* __restrict__ W1,
                                              _Float16* __restrict__ whi,
                                              _Float16* __restrict__ wlo) {
    int idx = blockIdx.x * 256 + threadIdx.x;
    int j    = idx & 7;
    int lane = (idx >> 3) & 63;
    int nt   = (idx >> 9) & 15;
    int kt   = idx >> 13;
    int k = kt * 32 + ((lane >> 4) & 3) * 8 + j;
    int n = nt * 16 + (lane & 15);
    float x = W1[k * FF + n];
    _Float16 hi = (_Float16)x;
    _Float16 lo = (_Float16)(x - (float)hi);
    whi[idx] = hi;
    wlo[idx] = lo;
}

// ---- fused kernel: barrier-free M-split GEMM ----
// 256 threads / 4 waves; wave w owns rows 16w..16w+15 x all 256 cols.
// A in registers (hi/lo half8, 64 VGPR) loaded once from HBM -> no LDS
// staging, no GEMM barriers. B streamed from L2-hot whi/wlo in 2-deep
// pipelined 32-reg chunks; chunk order alternates two acc chains so MFMA
// dep-latency is covered at 2 waves/SIMD. Wave-local layer-2 fold;
// redundant per-wave softmax; only 2 barriers total (SP, red).
__global__ __launch_bounds__(256, 2) void ida_mfma(
    const float* __restrict__ features,
    const float* __restrict__ src_locs,
    const float* __restrict__ tar_locs,
    const _Float16* __restrict__ whi,
    const _Float16* __restrict__ wlo,
    const float* __restrict__ b1,
    const float* __restrict__ W2,
    const float* __restrict__ b2,
    float* __restrict__ out)
{
    __shared__ float SP[LL];         // 64 station scores
    __shared__ float red[4][FF];     // cross-wave weighted-sum reduce (4 KiB)

    const int t    = threadIdx.x;
    const int wv   = t >> 6;         // wave 0..3 -> owns rows 16wv..16wv+15
    const int lane = t & 63;
    const int quad = lane >> 4;
    const int l16  = lane & 15;
    const int bs   = blockIdx.x;
    const int b    = bs / SS;

    const float* Xg = features + (size_t)bs * (LL * FF);

    // ---- A raw loads: lane holds row (16wv+l16), k = kt*32 + quad*8 + j ----
    float4 araw[16];
    const float* Arow = Xg + (wv * 16 + l16) * FF;
    #pragma unroll
    for (int kt = 0; kt < 8; ++kt) {
        const float4* p = (const float4*)(Arow + kt * 32 + quad * 8);
        araw[2 * kt + 0] = p[0];
        araw[2 * kt + 1] = p[1];
    }

    // ---- B chunk 0 (nt=0, kh=0) into buffer 0 ----
    half8 cbh[2][4], cbl[2][4];
    #pragma unroll
    for (int k2 = 0; k2 < 4; ++k2) {
        size_t off = ((size_t)(k2 * 16 + 0) * 64 + lane) * 8;
        cbh[0][k2] = *((const half8*)(whi + off));
        cbl[0][k2] = *((const half8*)(wlo + off));
    }

    // ---- inverse-distance (all lanes; station = lane; hides under loads) ----
    float dx = src_locs[(b * LL + lane) * 2 + 0] - tar_locs[b * 2 + 0];
    float dy = src_locs[(b * LL + lane) * 2 + 1] - tar_locs[b * 2 + 1];
    float inv_d = 1.0f / sqrtf(dx * dx + dy * dy);
    float b2v = b2[0];

    // ---- cvt A to hi/lo fragments (araw dies, ahi/alo born) ----
    half8 ahi[8], alo[8];
    #pragma unroll
    for (int kt = 0; kt < 8; ++kt) {
        float xs[8] = {araw[2 * kt].x,     araw[2 * kt].y,     araw[2 * kt].z,     araw[2 * kt].w,
                       araw[2 * kt + 1].x, araw[2 * kt + 1].y, araw[2 * kt + 1].z, araw[2 * kt + 1].w};
        #pragma unroll
        for (int j = 0; j < 8; ++j) {
            _Float16 h = (_Float16)xs[j];
            ahi[kt][j] = h;
            alo[kt][j] = (_Float16)(xs[j] - (float)h);
        }
    }

    floatx4 acc[16] = {};            // acc[nt] -> 64 AGPRs
    float b1v[16], w2v[16];

    // ---- barrier-free GEMM: 32 chunks, 2-deep B pipeline ----
    // chunk i: p=i>>2, q=i&3 -> nt = 2p+(q&1), kh = q>>1
    // consecutive chunks alternate acc[2p]/acc[2p+1] dep chains.
    #pragma unroll
    for (int i = 0; i < 32; ++i) {
        const int p   = i >> 2;
        const int q   = i & 3;
        const int nt  = 2 * p + (q & 1);
        const int kh  = q >> 1;
        const int cur = i & 1;
        if (i < 31) {
            const int i2  = i + 1;
            const int p2  = i2 >> 2, q2 = i2 & 3;
            const int nt2 = 2 * p2 + (q2 & 1);
            const int kh2 = q2 >> 1;
            #pragma unroll
            for (int k2 = 0; k2 < 4; ++k2) {
                size_t off = ((size_t)((kh2 * 4 + k2) * 16 + nt2) * 64 + lane) * 8;
                cbh[cur ^ 1][k2] = *((const half8*)(whi + off));
                cbl[cur ^ 1][k2] = *((const half8*)(wlo + off));
            }
        } else {
            // last chunk's free prefetch slot: epilogue operands (L2/L1-hot)
            #pragma unroll
            for (int n2 = 0; n2 < 16; ++n2) {
                b1v[n2] = b1[n2 * 16 + l16];
                w2v[n2] = W2[n2 * 16 + l16];
            }
        }
        #pragma unroll
        for (int k2 = 0; k2 < 4; ++k2) {
            const int kt = kh * 4 + k2;
            acc[nt] = __builtin_amdgcn_mfma_f32_16x16x32_f16(ahi[kt], cbh[cur][k2], acc[nt], 0, 0, 0);
            acc[nt] = __builtin_amdgcn_mfma_f32_16x16x32_f16(ahi[kt], cbl[cur][k2], acc[nt], 0, 0, 0);
            acc[nt] = __builtin_amdgcn_mfma_f32_16x16x32_f16(alo[kt], cbh[cur][k2], acc[nt], 0, 0, 0);
        }
    }

    // ---- issue wsum feature re-reads now (L3-hot); consumed after softmax ----
    float4 xraw[16];
    const float4* Xg4 = (const float4*)Xg;
    #pragma unroll
    for (int lr = 0; lr < 16; ++lr)
        xraw[lr] = Xg4[(wv * 16 + lr) * 64 + lane];

    // ---- wave-local layer-2 fold: score rows 16wv+quad*4+r ----
    #pragma unroll
    for (int r = 0; r < 4; ++r) {
        float pr = 0.f;
        #pragma unroll
        for (int nt = 0; nt < 16; ++nt) {
            float h = fmaxf(acc[nt][r] + b1v[nt], 0.f);
            pr = fmaf(h, w2v[nt], pr);
        }
        pr += __shfl_xor(pr, 1);
        pr += __shfl_xor(pr, 2);
        pr += __shfl_xor(pr, 4);
        pr += __shfl_xor(pr, 8);
        if (l16 == 0) SP[wv * 16 + quad * 4 + r] = pr;
    }
    __syncthreads();

    // ---- redundant per-wave softmax (station = lane) ----
    float s = SP[lane] + b2v;
    float score = fmaxf(s, 0.f);
    float logit = score * inv_d;
    float m = logit;
    #pragma unroll
    for (int o = 32; o > 0; o >>= 1) m = fmaxf(m, __shfl_xor(m, o));
    float e = __expf(logit - m);
    float se = e;
    #pragma unroll
    for (int o = 32; o > 0; o >>= 1) se += __shfl_xor(se, o);
    float wgt = e / se;   // weight of station `lane`, valid in all lanes

    // ---- weighted sum: wave w covers rows 16w..16w+15, lane = col-float4 ----
    {
        floatx4 o4 = {0.f, 0.f, 0.f, 0.f};
        #pragma unroll
        for (int lr = 0; lr < 16; ++lr) {
            float wl = __shfl(wgt, wv * 16 + lr);
            o4[0] = fmaf(xraw[lr].x, wl, o4[0]);
            o4[1] = fmaf(xraw[lr].y, wl, o4[1]);
            o4[2] = fmaf(xraw[lr].z, wl, o4[2]);
            o4[3] = fmaf(xraw[lr].w, wl, o4[3]);
        }
        *((floatx4*)&red[wv][lane * 4]) = o4;
    }
    __syncthreads();
    {
        float oo = red[0][t] + red[1][t] + red[2][t] + red[3][t];
        out[(size_t)bs * FF + t] = oo;
    }
}

extern "C" void kernel_launch(void* const* d_in, const int* in_sizes, int n_in,
                              void* d_out, int out_size, void* d_ws, size_t ws_size,
                              hipStream_t stream) {
    const float* features = (const float*)d_in[0];
    const float* src_locs = (const float*)d_in[1];
    const float* tar_locs = (const float*)d_in[2];
    const float* W1       = (const float*)d_in[3];
    const float* b1       = (const float*)d_in[4];
    const float* W2       = (const float*)d_in[5];
    const float* b2       = (const float*)d_in[6];
    float* out = (float*)d_out;

    _Float16* whi = (_Float16*)d_ws;               // 128 KiB
    _Float16* wlo = whi + FF * FF;                 // 128 KiB

    prep_w<<<dim3(FF * FF / 256), dim3(256), 0, stream>>>(W1, whi, wlo);
    ida_mfma<<<dim3(BB * SS), dim3(256), 0, stream>>>(
        features, src_locs, tar_locs, whi, wlo, b1, W2, b2, out);
}

// Round 4
// 183.100 us; speedup vs baseline: 1.2793x; 1.2793x over previous
//
#include <hip/hip_runtime.h>
#include <hip/hip_fp16.h>
#include <math.h>

typedef _Float16 half8 __attribute__((ext_vector_type(8)));
typedef float floatx4 __attribute__((ext_vector_type(4)));

#define BB 32
#define SS 48
#define LL 64
#define FF 256

// LDS-publish-only barrier: does NOT drain vmcnt, so global->VGPR prefetches
// stay in flight across it (unlike __syncthreads, which drains vmcnt(0)).
// All inter-wave data here moves through LDS => lgkmcnt(0) suffices.
#define WAVE_BARRIER() do {                                          \
    asm volatile("s_waitcnt lgkmcnt(0)" ::: "memory");               \
    __builtin_amdgcn_s_barrier();                                    \
    asm volatile("" ::: "memory");                                   \
} while (0)

// pin VMEM issue order so in-order vmcnt waits never cascade-drain a prefetch
#define ISSUE_FENCE() asm volatile("" ::: "memory")

// ---- prep (proven): W1 -> fp16 hi/lo MFMA-B fragment order ----
//   flat = ((kt*16 + nt)*64 + lane)*8 + j ; element = W1[kt*32+(lane>>4)*8+j][nt*16+(lane&15)]
__global__ __launch_bounds__(256) void prep_w(const float* __restrict__ W1,
                                              _Float16* __restrict__ whi,
                                              _Float16* __restrict__ wlo) {
    int idx = blockIdx.x * 256 + threadIdx.x;
    int j    = idx & 7;
    int lane = (idx >> 3) & 63;
    int nt   = (idx >> 9) & 15;
    int kt   = idx >> 13;
    int k = kt * 32 + ((lane >> 4) & 3) * 8 + j;
    int n = nt * 16 + (lane & 15);
    float x = W1[k * FF + n];
    _Float16 hi = (_Float16)x;
    _Float16 lo = (_Float16)(x - (float)hi);
    whi[idx] = hi;
    wlo[idx] = lo;
}

// ---- fused kernel: R2 skeleton + non-draining barriers + issue-order fix ----
// 512 thr / 8 waves, N-split (wave w owns cols 32w..32w+31). VMEM issue order:
// A0 -> B0 -> a1raw  (h0's B-wait leaves a1raw in flight across BAR1);
// b1/W2 issued after BAR1; xraw issued after h1, consumed after softmax.
__global__ __launch_bounds__(512, 4) void ida_mfma(
    const float* __restrict__ features,
    const float* __restrict__ src_locs,
    const float* __restrict__ tar_locs,
    const _Float16* __restrict__ whi,
    const _Float16* __restrict__ wlo,
    const float* __restrict__ b1,
    const float* __restrict__ W2,
    const float* __restrict__ b2,
    float* __restrict__ out)
{
    __shared__ __align__(16) unsigned char smem[32768];
    _Float16* Ahi = (_Float16*)smem;            // 16 KiB: [(mt*4+ktl)*64 + lane]*8
    _Float16* Alo = (_Float16*)(smem + 16384);  // 16 KiB
    // epilogue aliases (valid only after the post-h1 barrier):
    float* SP  = (float*)smem;                  // [row][wave] 512 floats
    float* red = SP + LL * 8;                   // 2048 floats

    const int t    = threadIdx.x;
    const int w    = t >> 6;         // wave 0..7 -> owns cols 32w..32w+31
    const int lane = t & 63;
    const int quad = lane >> 4;
    const int l16  = lane & 15;
    const int bs   = blockIdx.x;
    const int b    = bs / SS;

    const float* Xg = features + (size_t)bs * (LL * FF);

    // ---- misc loads first (values held raw; arithmetic deferred to use) ----
    float sx = src_locs[(b * LL + lane) * 2 + 0];
    float sy = src_locs[(b * LL + lane) * 2 + 1];
    float tx = tar_locs[b * 2 + 0];
    float ty = tar_locs[b * 2 + 1];
    float b2v = b2[0];
    ISSUE_FENCE();

    // ---- A0 raw loads (4 float4/thread) ----
    float4 a0raw[4];
    #pragma unroll
    for (int it = 0; it < 2; ++it) {
        int g   = it * 8 + w;
        int row = (g >> 2) * 16 + l16;
        int kc  = (g & 3) * 32 + quad * 8;
        const float4* p = (const float4*)(Xg + row * FF + kc);
        a0raw[2 * it + 0] = p[0];
        a0raw[2 * it + 1] = p[1];
    }
    ISSUE_FENCE();

    // ---- B0 preload (h0, ktl=0) BEFORE a1raw: h0's B-wait leaves a1raw in flight ----
    half8 bh[2], bl[2], nbh[2], nbl[2];
    #pragma unroll
    for (int ntl = 0; ntl < 2; ++ntl) {
        size_t off = ((size_t)(0 * 16 + (w * 2 + ntl)) * 64 + lane) * 8;
        bh[ntl] = *((const half8*)(whi + off));
        bl[ntl] = *((const half8*)(wlo + off));
    }
    ISSUE_FENCE();

    // ---- A1 raw loads: in flight across BAR1 + all of h0 ----
    float4 a1raw[4];
    #pragma unroll
    for (int it = 0; it < 2; ++it) {
        int g   = it * 8 + w;
        int row = (g >> 2) * 16 + l16;
        int kc  = (g & 3) * 32 + quad * 8;
        const float4* p = (const float4*)(Xg + row * FF + 128 + kc);
        a1raw[2 * it + 0] = p[0];
        a1raw[2 * it + 1] = p[1];
    }
    ISSUE_FENCE();

    // ---- stage half 0 (cvt waits a0raw only; B0/a1raw stay outstanding) ----
    #pragma unroll
    for (int it = 0; it < 2; ++it) {
        int g = it * 8 + w;
        float4 x0 = a0raw[2 * it + 0], x1 = a0raw[2 * it + 1];
        float xs[8] = {x0.x, x0.y, x0.z, x0.w, x1.x, x1.y, x1.z, x1.w};
        half8 hi, lo;
        #pragma unroll
        for (int j = 0; j < 8; ++j) {
            _Float16 h = (_Float16)xs[j];
            hi[j] = h;
            lo[j] = (_Float16)(xs[j] - (float)h);
        }
        *((half8*)&Ahi[(g * 64 + lane) * 8]) = hi;
        *((half8*)&Alo[(g * 64 + lane) * 8]) = lo;
    }

    WAVE_BARRIER();   // BAR1: A0 published; a1raw + B0 remain in flight

    floatx4 acc[4][2] = {};          // [mt][ntl] -> 32 AGPRs

    // ---- epilogue operands: issued early, drained incidentally, L2-hot ----
    float b1v[2], w2v[2];
    #pragma unroll
    for (int ntl = 0; ntl < 2; ++ntl) {
        int n = (w * 2 + ntl) * 16 + l16;
        b1v[ntl] = b1[n];
        w2v[ntl] = W2[n];
    }

    // ---- compute one K-half: per-ktl B prefetch + MFMA ----
#define COMPUTE_HALF(h)                                                          \
    _Pragma("unroll")                                                            \
    for (int ktl = 0; ktl < 4; ++ktl) {                                          \
        if (ktl < 3) {                                                           \
            _Pragma("unroll")                                                    \
            for (int ntl = 0; ntl < 2; ++ntl) {                                  \
                size_t off = ((size_t)(((h) * 4 + ktl + 1) * 16 + (w * 2 + ntl)) * 64 + lane) * 8; \
                nbh[ntl] = *((const half8*)(whi + off));                         \
                nbl[ntl] = *((const half8*)(wlo + off));                         \
            }                                                                    \
        }                                                                        \
        _Pragma("unroll")                                                        \
        for (int mt = 0; mt < 4; ++mt) {                                         \
            half8 ahi = *((half8*)&Ahi[((mt * 4 + ktl) * 64 + lane) * 8]);       \
            half8 alo = *((half8*)&Alo[((mt * 4 + ktl) * 64 + lane) * 8]);       \
            _Pragma("unroll")                                                    \
            for (int ntl = 0; ntl < 2; ++ntl) {                                  \
                acc[mt][ntl] = __builtin_amdgcn_mfma_f32_16x16x32_f16(ahi, bh[ntl], acc[mt][ntl], 0, 0, 0); \
                acc[mt][ntl] = __builtin_amdgcn_mfma_f32_16x16x32_f16(ahi, bl[ntl], acc[mt][ntl], 0, 0, 0); \
                acc[mt][ntl] = __builtin_amdgcn_mfma_f32_16x16x32_f16(alo, bh[ntl], acc[mt][ntl], 0, 0, 0); \
            }                                                                    \
        }                                                                        \
        if (ktl < 3) {                                                           \
            bh[0] = nbh[0]; bh[1] = nbh[1];                                      \
            bl[0] = nbl[0]; bl[1] = nbl[1];                                      \
        }                                                                        \
    }

    // ---- compute half 0 ----
    COMPUTE_HALF(0)

    // ---- preload B for half 1, ktl 0 ----
    #pragma unroll
    for (int ntl = 0; ntl < 2; ++ntl) {
        size_t off = ((size_t)(4 * 16 + (w * 2 + ntl)) * 64 + lane) * 8;
        bh[ntl] = *((const half8*)(whi + off));
        bl[ntl] = *((const half8*)(wlo + off));
    }

    WAVE_BARRIER();   // BAR2: half-0 LDS reads complete before overwrite; B(h1) in flight

    // ---- stage half 1 (cvt waits a1raw only; B(h1) stays outstanding) ----
    #pragma unroll
    for (int it = 0; it < 2; ++it) {
        int g = it * 8 + w;
        float4 x0 = a1raw[2 * it + 0], x1 = a1raw[2 * it + 1];
        float xs[8] = {x0.x, x0.y, x0.z, x0.w, x1.x, x1.y, x1.z, x1.w};
        half8 hi, lo;
        #pragma unroll
        for (int j = 0; j < 8; ++j) {
            _Float16 h = (_Float16)xs[j];
            hi[j] = h;
            lo[j] = (_Float16)(xs[j] - (float)h);
        }
        *((half8*)&Ahi[(g * 64 + lane) * 8]) = hi;
        *((half8*)&Alo[(g * 64 + lane) * 8]) = lo;
    }

    WAVE_BARRIER();   // BAR3: A1 published

    // ---- compute half 1 ----
    COMPUTE_HALF(1)
#undef COMPUTE_HALF

    // ---- xraw: wsum feature re-read (L1/L2-hot), in flight across fold+softmax ----
    float4 xraw[8];
    {
        const float4* Xg4 = (const float4*)Xg;
        #pragma unroll
        for (int lr = 0; lr < 8; ++lr)
            xraw[lr] = Xg4[(w * 8 + lr) * 64 + lane];
    }
    ISSUE_FENCE();

    WAVE_BARRIER();   // BAR4: all GEMM LDS reads done before epilogue aliases A-space

    // ---- layer-2 fold (8 waves x 2 nt) ----
    #pragma unroll
    for (int mt = 0; mt < 4; ++mt) {
        #pragma unroll
        for (int r = 0; r < 4; ++r) {
            float p = 0.f;
            #pragma unroll
            for (int ntl = 0; ntl < 2; ++ntl) {
                float h = fmaxf(acc[mt][ntl][r] + b1v[ntl], 0.f);
                p = fmaf(h, w2v[ntl], p);
            }
            p += __shfl_xor(p, 1);
            p += __shfl_xor(p, 2);
            p += __shfl_xor(p, 4);
            p += __shfl_xor(p, 8);
            if (l16 == 0) SP[(mt * 16 + quad * 4 + r) * 8 + w] = p;
        }
    }

    WAVE_BARRIER();   // BAR5: SP published

    // ---- redundant per-wave softmax (station = lane; no extra barrier) ----
    float s = SP[8 * lane + 0] + SP[8 * lane + 1] + SP[8 * lane + 2] + SP[8 * lane + 3]
            + SP[8 * lane + 4] + SP[8 * lane + 5] + SP[8 * lane + 6] + SP[8 * lane + 7] + b2v;
    float score = fmaxf(s, 0.f);
    float dxv = sx - tx, dyv = sy - ty;
    float inv_d = 1.0f / sqrtf(dxv * dxv + dyv * dyv);
    float logit = score * inv_d;
    float m = logit;
    #pragma unroll
    for (int o = 32; o > 0; o >>= 1) m = fmaxf(m, __shfl_xor(m, o));
    float e = __expf(logit - m);
    float se = e;
    #pragma unroll
    for (int o = 32; o > 0; o >>= 1) se += __shfl_xor(se, o);
    float wgt = e / se;   // weight of station `lane`, valid in all lanes of every wave

    // ---- weighted sum: wave w covers rows 8w..8w+7, lane = col-float4 ----
    {
        floatx4 o4 = {0.f, 0.f, 0.f, 0.f};
        #pragma unroll
        for (int lr = 0; lr < 8; ++lr) {
            float wl = __shfl(wgt, w * 8 + lr);
            o4[0] = fmaf(xraw[lr].x, wl, o4[0]);
            o4[1] = fmaf(xraw[lr].y, wl, o4[1]);
            o4[2] = fmaf(xraw[lr].z, wl, o4[2]);
            o4[3] = fmaf(xraw[lr].w, wl, o4[3]);
        }
        *((floatx4*)&red[w * FF + lane * 4]) = o4;
    }

    WAVE_BARRIER();   // BAR6: red published

    if (t < FF) {
        float o = red[0 * FF + t] + red[1 * FF + t] + red[2 * FF + t] + red[3 * FF + t]
                + red[4 * FF + t] + red[5 * FF + t] + red[6 * FF + t] + red[7 * FF + t];
        out[(size_t)bs * FF + t] = o;
    }
}

extern "C" void kernel_launch(void* const* d_in, const int* in_sizes, int n_in,
                              void* d_out, int out_size, void* d_ws, size_t ws_size,
                              hipStream_t stream) {
    const float* features = (const float*)d_in[0];
    const float* src_locs = (const float*)d_in[1];
    const float* tar_locs = (const float*)d_in[2];
    const float* W1       = (const float*)d_in[3];
    const float* b1       = (const float*)d_in[4];
    const float* W2       = (const float*)d_in[5];
    const float* b2       = (const float*)d_in[6];
    float* out = (float*)d_out;

    _Float16* whi = (_Float16*)d_ws;               // 128 KiB
    _Float16* wlo = whi + FF * FF;                 // 128 KiB

    prep_w<<<dim3(FF * FF / 256), dim3(256), 0, stream>>>(W1, whi, wlo);
    ida_mfma<<<dim3(BB * SS), dim3(512), 0, stream>>>(
        features, src_locs, tar_locs, whi, wlo, b1, W2, b2, out);
}

// Round 5
// 182.712 us; speedup vs baseline: 1.2820x; 1.0021x over previous
//
#include <hip/hip_runtime.h>
#include <hip/hip_fp16.h>
#include <math.h>

typedef _Float16 half8 __attribute__((ext_vector_type(8)));
typedef _Float16 half4_t __attribute__((ext_vector_type(4)));
typedef float floatx4 __attribute__((ext_vector_type(4)));

#define BB 32
#define SS 48
#define LL 64
#define FF 256

// LDS-publish-only barrier: does NOT drain vmcnt (global->VGPR prefetches
// stay in flight). All inter-wave data moves through LDS => lgkmcnt(0) suffices.
#define WAVE_BARRIER() do {                                          \
    asm volatile("s_waitcnt lgkmcnt(0)" ::: "memory");               \
    __builtin_amdgcn_s_barrier();                                    \
    asm volatile("" ::: "memory");                                   \
} while (0)

#define ISSUE_FENCE() asm volatile("" ::: "memory")

// ---- prep (proven): W1 -> fp16 hi/lo MFMA-B fragment order ----
//   flat = ((kt*16 + nt)*64 + lane)*8 + j ; element = W1[kt*32+(lane>>4)*8+j][nt*16+(lane&15)]
__global__ __launch_bounds__(256) void prep_w(const float* __restrict__ W1,
                                              _Float16* __restrict__ whi,
                                              _Float16* __restrict__ wlo) {
    int idx = blockIdx.x * 256 + threadIdx.x;
    int j    = idx & 7;
    int lane = (idx >> 3) & 63;
    int nt   = (idx >> 9) & 15;
    int kt   = idx >> 13;
    int k = kt * 32 + ((lane >> 4) & 3) * 8 + j;
    int n = nt * 16 + (lane & 15);
    float x = W1[k * FF + n];
    _Float16 hi = (_Float16)x;
    _Float16 lo = (_Float16)(x - (float)hi);
    whi[idx] = hi;
    wlo[idx] = lo;
}

// ---- fused kernel: work-cut round ----
// (1) A-side lo term dropped: acc = a_hi*b_hi + a_hi*b_lo (2 MFMAs, was 3).
//     Err est ~0.01-0.02 absmax vs known-pass >= 0.0685.
// (2) A staged ONCE as fp16 (full K=256, 32 KiB), never overwritten:
//     no two-half restage, 3 barriers total; weighted-sum reads features
//     from LDS (fp16) instead of re-reading 64 KB/block from global.
// A-fragment LDS layout: element (row r, col c) at
//     Ahi[(G*64 + ((c>>3)&3)*16 + (r&15))*8 + (c&7)],  G = (r>>4)*8 + (c>>5)
__global__ __launch_bounds__(512, 4) void ida_mfma(
    const float* __restrict__ features,
    const float* __restrict__ src_locs,
    const float* __restrict__ tar_locs,
    const _Float16* __restrict__ whi,
    const _Float16* __restrict__ wlo,
    const float* __restrict__ b1,
    const float* __restrict__ W2,
    const float* __restrict__ b2,
    float* __restrict__ out)
{
    __shared__ _Float16 Ahi[16384];   // 32 KiB: full 64x256 A in fp16
    __shared__ float SP[LL * 8];      // layer-2 partials [row][wave]
    __shared__ float red[8 * FF];     // weighted-sum cross-wave reduce

    const int t    = threadIdx.x;
    const int w    = t >> 6;          // wave 0..7 -> owns cols 32w..32w+31
    const int lane = t & 63;
    const int quad = lane >> 4;
    const int l16  = lane & 15;
    const int bs   = blockIdx.x;
    const int b    = bs / SS;

    const float* Xg = features + (size_t)bs * (LL * FF);

    // ---- misc loads first (consumed late; drained incidentally) ----
    float sx = src_locs[(b * LL + lane) * 2 + 0];
    float sy = src_locs[(b * LL + lane) * 2 + 1];
    float tx = tar_locs[b * 2 + 0];
    float ty = tar_locs[b * 2 + 1];
    float b2v = b2[0];
    float b1v[2], w2v[2];
    #pragma unroll
    for (int ntl = 0; ntl < 2; ++ntl) {
        int n = (w * 2 + ntl) * 16 + l16;
        b1v[ntl] = b1[n];
        w2v[ntl] = W2[n];
    }
    ISSUE_FENCE();

    // ---- A raw loads: 4 G-groups/thread, G = it*8+w ----
    float4 araw[8];
    #pragma unroll
    for (int it = 0; it < 4; ++it) {
        int G   = it * 8 + w;
        int row = (G >> 3) * 16 + l16;     // = it*16 + l16
        int cb  = (G & 7) * 32 + quad * 8; // = w*32 + quad*8
        const float4* p = (const float4*)(Xg + row * FF + cb);
        araw[2 * it + 0] = p[0];
        araw[2 * it + 1] = p[1];
    }
    ISSUE_FENCE();

    // ---- B preload (kt=0) AFTER araw: waiting araw leaves B0 in flight ----
    half8 bh[2], bl[2], nbh[2], nbl[2];
    #pragma unroll
    for (int ntl = 0; ntl < 2; ++ntl) {
        size_t off = ((size_t)(0 * 16 + (w * 2 + ntl)) * 64 + lane) * 8;
        bh[ntl] = *((const half8*)(whi + off));
        bl[ntl] = *((const half8*)(wlo + off));
    }
    ISSUE_FENCE();

    // ---- stage A (cvt to fp16 hi only, 4 half8 writes/thread) ----
    #pragma unroll
    for (int it = 0; it < 4; ++it) {
        int G = it * 8 + w;
        float4 x0 = araw[2 * it + 0], x1 = araw[2 * it + 1];
        float xs[8] = {x0.x, x0.y, x0.z, x0.w, x1.x, x1.y, x1.z, x1.w};
        half8 hi;
        #pragma unroll
        for (int j = 0; j < 8; ++j) hi[j] = (_Float16)xs[j];
        *((half8*)&Ahi[(G * 64 + lane) * 8]) = hi;
    }

    WAVE_BARRIER();   // BAR1: A published; B0 still in flight

    floatx4 acc[4][2] = {};   // [mt][ntl] -> 32 AGPRs

    // ---- GEMM: 8 kt steps, 2-deep B pipeline, 2 MFMA per (kt,mt,ntl) ----
    #pragma unroll
    for (int kt = 0; kt < 8; ++kt) {
        if (kt < 7) {
            #pragma unroll
            for (int ntl = 0; ntl < 2; ++ntl) {
                size_t off = ((size_t)((kt + 1) * 16 + (w * 2 + ntl)) * 64 + lane) * 8;
                nbh[ntl] = *((const half8*)(whi + off));
                nbl[ntl] = *((const half8*)(wlo + off));
            }
        }
        #pragma unroll
        for (int mt = 0; mt < 4; ++mt) {
            half8 ahi = *((half8*)&Ahi[((mt * 8 + kt) * 64 + lane) * 8]);
            #pragma unroll
            for (int ntl = 0; ntl < 2; ++ntl) {
                acc[mt][ntl] = __builtin_amdgcn_mfma_f32_16x16x32_f16(ahi, bh[ntl], acc[mt][ntl], 0, 0, 0);
                acc[mt][ntl] = __builtin_amdgcn_mfma_f32_16x16x32_f16(ahi, bl[ntl], acc[mt][ntl], 0, 0, 0);
            }
        }
        if (kt < 7) {
            bh[0] = nbh[0]; bh[1] = nbh[1];
            bl[0] = nbl[0]; bl[1] = nbl[1];
        }
    }

    // ---- layer-2 fold (acc regs only; no barrier needed before this) ----
    #pragma unroll
    for (int mt = 0; mt < 4; ++mt) {
        #pragma unroll
        for (int r = 0; r < 4; ++r) {
            float p = 0.f;
            #pragma unroll
            for (int ntl = 0; ntl < 2; ++ntl) {
                float h = fmaxf(acc[mt][ntl][r] + b1v[ntl], 0.f);
                p = fmaf(h, w2v[ntl], p);
            }
            p += __shfl_xor(p, 1);
            p += __shfl_xor(p, 2);
            p += __shfl_xor(p, 4);
            p += __shfl_xor(p, 8);
            if (l16 == 0) SP[(mt * 16 + quad * 4 + r) * 8 + w] = p;
        }
    }

    WAVE_BARRIER();   // BAR2: SP published

    // ---- redundant per-wave softmax (station = lane) ----
    float s = SP[8 * lane + 0] + SP[8 * lane + 1] + SP[8 * lane + 2] + SP[8 * lane + 3]
            + SP[8 * lane + 4] + SP[8 * lane + 5] + SP[8 * lane + 6] + SP[8 * lane + 7] + b2v;
    float score = fmaxf(s, 0.f);
    float dxv = sx - tx, dyv = sy - ty;
    float inv_d = 1.0f / sqrtf(dxv * dxv + dyv * dyv);
    float logit = score * inv_d;
    float m = logit;
    #pragma unroll
    for (int o = 32; o > 0; o >>= 1) m = fmaxf(m, __shfl_xor(m, o));
    float e = __expf(logit - m);
    float se = e;
    #pragma unroll
    for (int o = 32; o > 0; o >>= 1) se += __shfl_xor(se, o);
    float wgt = e / se;   // weight of station `lane`, valid in all lanes

    // ---- weighted sum from LDS fp16 features (no global re-read) ----
    // thread covers rows w*8..w*8+7, cols c = lane*4..lane*4+3
    {
        floatx4 o4 = {0.f, 0.f, 0.f, 0.f};
        #pragma unroll
        for (int lr = 0; lr < 8; ++lr) {
            int r  = w * 8 + lr;
            float wl = __shfl(wgt, r);
            int G2 = (r >> 4) * 8 + (lane >> 3);
            int ei = (G2 * 64 + ((lane >> 1) & 3) * 16 + (r & 15)) * 8 + (lane & 1) * 4;
            half4_t hv = *((const half4_t*)&Ahi[ei]);
            o4[0] = fmaf((float)hv[0], wl, o4[0]);
            o4[1] = fmaf((float)hv[1], wl, o4[1]);
            o4[2] = fmaf((float)hv[2], wl, o4[2]);
            o4[3] = fmaf((float)hv[3], wl, o4[3]);
        }
        *((floatx4*)&red[w * FF + lane * 4]) = o4;
    }

    WAVE_BARRIER();   // BAR3: red published

    if (t < FF) {
        float o = red[0 * FF + t] + red[1 * FF + t] + red[2 * FF + t] + red[3 * FF + t]
                + red[4 * FF + t] + red[5 * FF + t] + red[6 * FF + t] + red[7 * FF + t];
        out[(size_t)bs * FF + t] = o;
    }
}

extern "C" void kernel_launch(void* const* d_in, const int* in_sizes, int n_in,
                              void* d_out, int out_size, void* d_ws, size_t ws_size,
                              hipStream_t stream) {
    const float* features = (const float*)d_in[0];
    const float* src_locs = (const float*)d_in[1];
    const float* tar_locs = (const float*)d_in[2];
    const float* W1       = (const float*)d_in[3];
    const float* b1       = (const float*)d_in[4];
    const float* W2       = (const float*)d_in[5];
    const float* b2       = (const float*)d_in[6];
    float* out = (float*)d_out;

    _Float16* whi = (_Float16*)d_ws;               // 128 KiB
    _Float16* wlo = whi + FF * FF;                 // 128 KiB

    prep_w<<<dim3(FF * FF / 256), dim3(256), 0, stream>>>(W1, whi, wlo);
    ida_mfma<<<dim3(BB * SS), dim3(512), 0, stream>>>(
        features, src_locs, tar_locs, whi, wlo, b1, W2, b2, out);
}

// Round 6
// 176.051 us; speedup vs baseline: 1.3305x; 1.0378x over previous
//
#include <hip/hip_runtime.h>
#include <hip/hip_fp16.h>
#include <math.h>

typedef _Float16 half8 __attribute__((ext_vector_type(8)));
typedef float floatx4 __attribute__((ext_vector_type(4)));

#define BB 32
#define SS 48
#define LL 64
#define FF 256

// LDS-publish-only barrier: does NOT drain vmcnt (global->VGPR prefetches
// stay in flight). All inter-wave data moves through LDS => lgkmcnt(0) suffices.
#define WAVE_BARRIER() do {                                          \
    asm volatile("s_waitcnt lgkmcnt(0)" ::: "memory");               \
    __builtin_amdgcn_s_barrier();                                    \
    asm volatile("" ::: "memory");                                   \
} while (0)

#define ISSUE_FENCE() asm volatile("" ::: "memory")

// ---- prep: W1 -> fp16 MFMA-B fragment order (hi only; lo term dropped) ----
//   flat = ((kt*16 + nt)*64 + lane)*8 + j ; element = W1[kt*32+(lane>>4)*8+j][nt*16+(lane&15)]
__global__ __launch_bounds__(256) void prep_w(const float* __restrict__ W1,
                                              _Float16* __restrict__ whi) {
    int idx = blockIdx.x * 256 + threadIdx.x;
    int j    = idx & 7;
    int lane = (idx >> 3) & 63;
    int nt   = (idx >> 9) & 15;
    int kt   = idx >> 13;
    int k = kt * 32 + ((lane >> 4) & 3) * 8 + j;
    int n = nt * 16 + (lane & 15);
    whi[idx] = (_Float16)W1[k * FF + n];
}

// ---- fused kernel: deletion round ----
// (1) wsum reads Ahi along the staging-write pattern (contiguous 1KB/wave,
//     conflict-free; was a 32-way conflict = 5.6 us/CU) and reduces via
//     shfl_xor over l16; lane l16==0 per quad stores 8 cols DIRECT to global.
//     red[] buffer + BAR3 deleted.
// (2) b_lo MFMA term dropped: 1 MFMA per tile (est absmax ~0.025 vs 0.0685
//     known-pass); wlo never read -> half the B-stream L2 loads.
// (3) LDS 34.8 KB + launch_bounds(512,6) -> 3 blocks/CU concurrent.
__global__ __launch_bounds__(512, 6) void ida_mfma(
    const float* __restrict__ features,
    const float* __restrict__ src_locs,
    const float* __restrict__ tar_locs,
    const _Float16* __restrict__ whi,
    const float* __restrict__ b1,
    const float* __restrict__ W2,
    const float* __restrict__ b2,
    float* __restrict__ out)
{
    __shared__ _Float16 Ahi[16384];   // 32 KiB: full 64x256 A in fp16
    __shared__ float SP[LL * 8];      // layer-2 partials [row][wave] (2 KiB)

    const int t    = threadIdx.x;
    const int w    = t >> 6;          // wave 0..7 -> owns cols 32w..32w+31
    const int lane = t & 63;
    const int quad = lane >> 4;
    const int l16  = lane & 15;
    const int bs   = blockIdx.x;
    const int b    = bs / SS;

    const float* Xg = features + (size_t)bs * (LL * FF);

    // ---- misc loads first (consumed late; drained incidentally) ----
    float sx = src_locs[(b * LL + lane) * 2 + 0];
    float sy = src_locs[(b * LL + lane) * 2 + 1];
    float tx = tar_locs[b * 2 + 0];
    float ty = tar_locs[b * 2 + 1];
    float b2v = b2[0];
    float b1v[2], w2v[2];
    #pragma unroll
    for (int ntl = 0; ntl < 2; ++ntl) {
        int n = (w * 2 + ntl) * 16 + l16;
        b1v[ntl] = b1[n];
        w2v[ntl] = W2[n];
    }
    ISSUE_FENCE();

    // ---- A raw loads: 4 G-groups/thread, G = it*8+w ----
    float4 araw[8];
    #pragma unroll
    for (int it = 0; it < 4; ++it) {
        int G   = it * 8 + w;
        int row = (G >> 3) * 16 + l16;     // = it*16 + l16
        int cb  = (G & 7) * 32 + quad * 8; // = w*32 + quad*8
        const float4* p = (const float4*)(Xg + row * FF + cb);
        araw[2 * it + 0] = p[0];
        araw[2 * it + 1] = p[1];
    }
    ISSUE_FENCE();

    // ---- B preload (kt=0) AFTER araw: waiting araw leaves B0 in flight ----
    half8 bh[2], nbh[2];
    #pragma unroll
    for (int ntl = 0; ntl < 2; ++ntl) {
        size_t off = ((size_t)(0 * 16 + (w * 2 + ntl)) * 64 + lane) * 8;
        bh[ntl] = *((const half8*)(whi + off));
    }
    ISSUE_FENCE();

    // ---- stage A (cvt to fp16, 4 half8 writes/thread) ----
    // element (row r, col c) at Ahi[(G*64 + lane)*8 + j]:
    //   row = (G>>3)*16 + l16, col = (G&7)*32 + quad*8 + j
    #pragma unroll
    for (int it = 0; it < 4; ++it) {
        int G = it * 8 + w;
        float4 x0 = araw[2 * it + 0], x1 = araw[2 * it + 1];
        float xs[8] = {x0.x, x0.y, x0.z, x0.w, x1.x, x1.y, x1.z, x1.w};
        half8 hi;
        #pragma unroll
        for (int j = 0; j < 8; ++j) hi[j] = (_Float16)xs[j];
        *((half8*)&Ahi[(G * 64 + lane) * 8]) = hi;
    }

    WAVE_BARRIER();   // BAR1: A published; B0 still in flight

    floatx4 acc[4][2] = {};   // [mt][ntl] -> 32 AGPRs

    // ---- GEMM: 8 kt steps, 2-deep B pipeline, 1 MFMA per (kt,mt,ntl) ----
    #pragma unroll
    for (int kt = 0; kt < 8; ++kt) {
        if (kt < 7) {
            #pragma unroll
            for (int ntl = 0; ntl < 2; ++ntl) {
                size_t off = ((size_t)((kt + 1) * 16 + (w * 2 + ntl)) * 64 + lane) * 8;
                nbh[ntl] = *((const half8*)(whi + off));
            }
        }
        #pragma unroll
        for (int mt = 0; mt < 4; ++mt) {
            half8 ahi = *((half8*)&Ahi[((mt * 8 + kt) * 64 + lane) * 8]);
            #pragma unroll
            for (int ntl = 0; ntl < 2; ++ntl)
                acc[mt][ntl] = __builtin_amdgcn_mfma_f32_16x16x32_f16(ahi, bh[ntl], acc[mt][ntl], 0, 0, 0);
        }
        if (kt < 7) { bh[0] = nbh[0]; bh[1] = nbh[1]; }
    }

    // ---- layer-2 fold (acc regs only) ----
    #pragma unroll
    for (int mt = 0; mt < 4; ++mt) {
        #pragma unroll
        for (int r = 0; r < 4; ++r) {
            float p = 0.f;
            #pragma unroll
            for (int ntl = 0; ntl < 2; ++ntl) {
                float h = fmaxf(acc[mt][ntl][r] + b1v[ntl], 0.f);
                p = fmaf(h, w2v[ntl], p);
            }
            p += __shfl_xor(p, 1);
            p += __shfl_xor(p, 2);
            p += __shfl_xor(p, 4);
            p += __shfl_xor(p, 8);
            if (l16 == 0) SP[(mt * 16 + quad * 4 + r) * 8 + w] = p;
        }
    }

    WAVE_BARRIER();   // BAR2: SP published

    // ---- redundant per-wave softmax (station = lane) ----
    float s = SP[8 * lane + 0] + SP[8 * lane + 1] + SP[8 * lane + 2] + SP[8 * lane + 3]
            + SP[8 * lane + 4] + SP[8 * lane + 5] + SP[8 * lane + 6] + SP[8 * lane + 7] + b2v;
    float score = fmaxf(s, 0.f);
    float dxv = sx - tx, dyv = sy - ty;
    float inv_d = 1.0f / sqrtf(dxv * dxv + dyv * dyv);
    float logit = score * inv_d;
    float m = logit;
    #pragma unroll
    for (int o = 32; o > 0; o >>= 1) m = fmaxf(m, __shfl_xor(m, o));
    float e = __expf(logit - m);
    float se = e;
    #pragma unroll
    for (int o = 32; o > 0; o >>= 1) se += __shfl_xor(se, o);
    float wgt = e / se;   // weight of station `lane`, valid in all lanes

    // ---- weighted sum: read Ahi along the staging-write pattern (conflict-free) ----
    // thread accumulates rows {it*16+l16} for cols w*32+quad*8+[0..8)
    float o8[8] = {0.f, 0.f, 0.f, 0.f, 0.f, 0.f, 0.f, 0.f};
    #pragma unroll
    for (int it = 0; it < 4; ++it) {
        float wr = __shfl(wgt, it * 16 + l16);
        half8 hv = *((half8*)&Ahi[((it * 8 + w) * 64 + lane) * 8]);
        #pragma unroll
        for (int j = 0; j < 8; ++j)
            o8[j] = fmaf((float)hv[j], wr, o8[j]);
    }
    // reduce over l16 (rows) within each 16-lane group
    #pragma unroll
    for (int o = 1; o < 16; o <<= 1) {
        #pragma unroll
        for (int j = 0; j < 8; ++j)
            o8[j] += __shfl_xor(o8[j], o);
    }
    // lane l16==0 of each quad holds full sums for cols w*32+quad*8+[0..8)
    if (l16 == 0) {
        float* op = out + (size_t)bs * FF + w * 32 + quad * 8;
        float4 s0 = {o8[0], o8[1], o8[2], o8[3]};
        float4 s1 = {o8[4], o8[5], o8[6], o8[7]};
        *((float4*)op) = s0;
        *((float4*)(op + 4)) = s1;
    }
}

extern "C" void kernel_launch(void* const* d_in, const int* in_sizes, int n_in,
                              void* d_out, int out_size, void* d_ws, size_t ws_size,
                              hipStream_t stream) {
    const float* features = (const float*)d_in[0];
    const float* src_locs = (const float*)d_in[1];
    const float* tar_locs = (const float*)d_in[2];
    const float* W1       = (const float*)d_in[3];
    const float* b1       = (const float*)d_in[4];
    const float* W2       = (const float*)d_in[5];
    const float* b2       = (const float*)d_in[6];
    float* out = (float*)d_out;

    _Float16* whi = (_Float16*)d_ws;               // 128 KiB

    prep_w<<<dim3(FF * FF / 256), dim3(256), 0, stream>>>(W1, whi);
    ida_mfma<<<dim3(BB * SS), dim3(512), 0, stream>>>(
        features, src_locs, tar_locs, whi, b1, W2, b2, out);
}

// Round 7
// 171.894 us; speedup vs baseline: 1.3627x; 1.0242x over previous
//
#include <hip/hip_runtime.h>
#include <hip/hip_fp16.h>
#include <math.h>

typedef _Float16 half8 __attribute__((ext_vector_type(8)));
typedef float floatx4 __attribute__((ext_vector_type(4)));

#define BB 32
#define SS 48
#define LL 64
#define FF 256

// LDS-publish-only barrier: does NOT drain vmcnt (global->VGPR prefetches
// stay in flight). All inter-wave data moves through LDS => lgkmcnt(0) suffices.
#define WAVE_BARRIER() do {                                          \
    asm volatile("s_waitcnt lgkmcnt(0)" ::: "memory");               \
    __builtin_amdgcn_s_barrier();                                    \
    asm volatile("" ::: "memory");                                   \
} while (0)

#define ISSUE_FENCE() asm volatile("" ::: "memory")

// ---- DPP 16-lane reduces on the VALU (not the DS pipe) ----
// quad_perm xor1 = 0xB1, xor2 = 0x4E, row_ror:4 = 0x124, row_ror:8 = 0x128.
// After the 4 stages every lane of each 16-lane row holds the row total.
template <int CTRL>
__device__ __forceinline__ float dpp_add(float x) {
    int y = __builtin_amdgcn_update_dpp(0, __float_as_int(x), CTRL, 0xF, 0xF, true);
    return x + __int_as_float(y);
}
template <int CTRL>
__device__ __forceinline__ float dpp_max(float x) {
    int y = __builtin_amdgcn_update_dpp(0, __float_as_int(x), CTRL, 0xF, 0xF, true);
    return fmaxf(x, __int_as_float(y));
}
__device__ __forceinline__ float row16_sum(float x) {
    x = dpp_add<0xB1>(x);   // quad_perm xor1
    x = dpp_add<0x4E>(x);   // quad_perm xor2
    x = dpp_add<0x124>(x);  // row_ror:4
    x = dpp_add<0x128>(x);  // row_ror:8
    return x;
}
__device__ __forceinline__ float row16_max(float x) {
    x = dpp_max<0xB1>(x);
    x = dpp_max<0x4E>(x);
    x = dpp_max<0x124>(x);
    x = dpp_max<0x128>(x);
    return x;
}

// ---- prep: W1 -> fp16 MFMA-B fragment order (hi only) ----
//   flat = ((kt*16 + nt)*64 + lane)*8 + j ; element = W1[kt*32+(lane>>4)*8+j][nt*16+(lane&15)]
__global__ __launch_bounds__(256) void prep_w(const float* __restrict__ W1,
                                              _Float16* __restrict__ whi) {
    int idx = blockIdx.x * 256 + threadIdx.x;
    int j    = idx & 7;
    int lane = (idx >> 3) & 63;
    int nt   = (idx >> 9) & 15;
    int kt   = idx >> 13;
    int k = kt * 32 + ((lane >> 4) & 3) * 8 + j;
    int n = nt * 16 + (lane & 15);
    whi[idx] = (_Float16)W1[k * FF + n];
}

// ---- fused kernel: DS->VALU round ----
// All 16-lane reduces (fold, wsum) moved to DPP row ops on the VALU; the
// softmax's cross-row stages keep 2 shfl each. SP relaid to [wave][station]
// so softmax reads are lane-consecutive conflict-free b32s. DS-pipe busy
// per CU ~22.5 -> ~11 us (the GEMM ds_read_b128 stream remains).
__global__ __launch_bounds__(512, 6) void ida_mfma(
    const float* __restrict__ features,
    const float* __restrict__ src_locs,
    const float* __restrict__ tar_locs,
    const _Float16* __restrict__ whi,
    const float* __restrict__ b1,
    const float* __restrict__ W2,
    const float* __restrict__ b2,
    float* __restrict__ out)
{
    __shared__ _Float16 Ahi[16384];   // 32 KiB: full 64x256 A in fp16
    __shared__ float SP[8 * LL];      // layer-2 partials [wave][station] (2 KiB)

    const int t    = threadIdx.x;
    const int w    = t >> 6;          // wave 0..7 -> owns cols 32w..32w+31
    const int lane = t & 63;
    const int quad = lane >> 4;
    const int l16  = lane & 15;
    const int bs   = blockIdx.x;
    const int b    = bs / SS;

    const float* Xg = features + (size_t)bs * (LL * FF);

    // ---- misc loads first (consumed late; drained incidentally) ----
    float sx = src_locs[(b * LL + lane) * 2 + 0];
    float sy = src_locs[(b * LL + lane) * 2 + 1];
    float tx = tar_locs[b * 2 + 0];
    float ty = tar_locs[b * 2 + 1];
    float b2v = b2[0];
    float b1v[2], w2v[2];
    #pragma unroll
    for (int ntl = 0; ntl < 2; ++ntl) {
        int n = (w * 2 + ntl) * 16 + l16;
        b1v[ntl] = b1[n];
        w2v[ntl] = W2[n];
    }
    ISSUE_FENCE();

    // ---- A raw loads: 4 G-groups/thread, G = it*8+w ----
    float4 araw[8];
    #pragma unroll
    for (int it = 0; it < 4; ++it) {
        int G   = it * 8 + w;
        int row = (G >> 3) * 16 + l16;     // = it*16 + l16
        int cb  = (G & 7) * 32 + quad * 8; // = w*32 + quad*8
        const float4* p = (const float4*)(Xg + row * FF + cb);
        araw[2 * it + 0] = p[0];
        araw[2 * it + 1] = p[1];
    }
    ISSUE_FENCE();

    // ---- B preload (kt=0) AFTER araw: waiting araw leaves B0 in flight ----
    half8 bh[2], nbh[2];
    #pragma unroll
    for (int ntl = 0; ntl < 2; ++ntl) {
        size_t off = ((size_t)(0 * 16 + (w * 2 + ntl)) * 64 + lane) * 8;
        bh[ntl] = *((const half8*)(whi + off));
    }
    ISSUE_FENCE();

    // ---- stage A (cvt to fp16, 4 half8 writes/thread) ----
    // element (row r, col c) at Ahi[(G*64 + lane)*8 + j]:
    //   row = (G>>3)*16 + l16, col = (G&7)*32 + quad*8 + j
    #pragma unroll
    for (int it = 0; it < 4; ++it) {
        int G = it * 8 + w;
        float4 x0 = araw[2 * it + 0], x1 = araw[2 * it + 1];
        float xs[8] = {x0.x, x0.y, x0.z, x0.w, x1.x, x1.y, x1.z, x1.w};
        half8 hi;
        #pragma unroll
        for (int j = 0; j < 8; ++j) hi[j] = (_Float16)xs[j];
        *((half8*)&Ahi[(G * 64 + lane) * 8]) = hi;
    }

    WAVE_BARRIER();   // BAR1: A published; B0 still in flight

    floatx4 acc[4][2] = {};   // [mt][ntl] -> 32 AGPRs

    // ---- GEMM: 8 kt steps, 2-deep B pipeline, 1 MFMA per (kt,mt,ntl) ----
    #pragma unroll
    for (int kt = 0; kt < 8; ++kt) {
        if (kt < 7) {
            #pragma unroll
            for (int ntl = 0; ntl < 2; ++ntl) {
                size_t off = ((size_t)((kt + 1) * 16 + (w * 2 + ntl)) * 64 + lane) * 8;
                nbh[ntl] = *((const half8*)(whi + off));
            }
        }
        #pragma unroll
        for (int mt = 0; mt < 4; ++mt) {
            half8 ahi = *((half8*)&Ahi[((mt * 8 + kt) * 64 + lane) * 8]);
            #pragma unroll
            for (int ntl = 0; ntl < 2; ++ntl)
                acc[mt][ntl] = __builtin_amdgcn_mfma_f32_16x16x32_f16(ahi, bh[ntl], acc[mt][ntl], 0, 0, 0);
        }
        if (kt < 7) { bh[0] = nbh[0]; bh[1] = nbh[1]; }
    }

    // ---- layer-2 fold: DPP row-reduce (VALU), no DS shuffles ----
    // lane (quad,l16) holds partials for row mt*16+quad*4+r over its 2 cols;
    // row16_sum reduces the 16 l16-lanes; lane l16==0 publishes.
    #pragma unroll
    for (int mt = 0; mt < 4; ++mt) {
        #pragma unroll
        for (int r = 0; r < 4; ++r) {
            float p = 0.f;
            #pragma unroll
            for (int ntl = 0; ntl < 2; ++ntl) {
                float h = fmaxf(acc[mt][ntl][r] + b1v[ntl], 0.f);
                p = fmaf(h, w2v[ntl], p);
            }
            p = row16_sum(p);
            if (l16 == 0) SP[w * LL + mt * 16 + quad * 4 + r] = p;
        }
    }

    WAVE_BARRIER();   // BAR2: SP published

    // ---- redundant per-wave softmax (station = lane; conflict-free SP reads) ----
    float s = SP[0 * LL + lane] + SP[1 * LL + lane] + SP[2 * LL + lane] + SP[3 * LL + lane]
            + SP[4 * LL + lane] + SP[5 * LL + lane] + SP[6 * LL + lane] + SP[7 * LL + lane] + b2v;
    float score = fmaxf(s, 0.f);
    float dxv = sx - tx, dyv = sy - ty;
    float inv_d = 1.0f / sqrtf(dxv * dxv + dyv * dyv);
    float logit = score * inv_d;
    float m = row16_max(logit);                    // 4 DPP
    m = fmaxf(m, __shfl_xor(m, 16));
    m = fmaxf(m, __shfl_xor(m, 32));
    float e = __expf(logit - m);
    float se = row16_sum(e);                       // 4 DPP
    se += __shfl_xor(se, 16);
    se += __shfl_xor(se, 32);
    float wgt = e / se;   // weight of station `lane`, valid in all lanes

    // ---- weighted sum: Ahi read along staging pattern (conflict-free) +
    //      DPP row-reduce over l16 (rows); lane l16==0 stores 8 cols direct ----
    float o8[8] = {0.f, 0.f, 0.f, 0.f, 0.f, 0.f, 0.f, 0.f};
    #pragma unroll
    for (int it = 0; it < 4; ++it) {
        float wr = __shfl(wgt, it * 16 + l16);
        half8 hv = *((half8*)&Ahi[((it * 8 + w) * 64 + lane) * 8]);
        #pragma unroll
        for (int j = 0; j < 8; ++j)
            o8[j] = fmaf((float)hv[j], wr, o8[j]);
    }
    #pragma unroll
    for (int j = 0; j < 8; ++j)
        o8[j] = row16_sum(o8[j]);
    if (l16 == 0) {
        float* op = out + (size_t)bs * FF + w * 32 + quad * 8;
        float4 s0 = {o8[0], o8[1], o8[2], o8[3]};
        float4 s1 = {o8[4], o8[5], o8[6], o8[7]};
        *((float4*)op) = s0;
        *((float4*)(op + 4)) = s1;
    }
}

extern "C" void kernel_launch(void* const* d_in, const int* in_sizes, int n_in,
                              void* d_out, int out_size, void* d_ws, size_t ws_size,
                              hipStream_t stream) {
    const float* features = (const float*)d_in[0];
    const float* src_locs = (const float*)d_in[1];
    const float* tar_locs = (const float*)d_in[2];
    const float* W1       = (const float*)d_in[3];
    const float* b1       = (const float*)d_in[4];
    const float* W2       = (const float*)d_in[5];
    const float* b2       = (const float*)d_in[6];
    float* out = (float*)d_out;

    _Float16* whi = (_Float16*)d_ws;               // 128 KiB

    prep_w<<<dim3(FF * FF / 256), dim3(256), 0, stream>>>(W1, whi);
    ida_mfma<<<dim3(BB * SS), dim3(512), 0, stream>>>(
        features, src_locs, tar_locs, whi, b1, W2, b2, out);
}

// Round 8
// 164.432 us; speedup vs baseline: 1.4245x; 1.0454x over previous
//
#include <hip/hip_runtime.h>
#include <hip/hip_fp16.h>
#include <math.h>

typedef _Float16 half8 __attribute__((ext_vector_type(8)));
typedef float floatx4 __attribute__((ext_vector_type(4)));

#define BB 32
#define SS 48
#define LL 64
#define FF 256
#define NSLICE 3
#define NBLK ((BB * SS) / NSLICE)   // 512 blocks, exactly 2 per CU

// LDS-publish-only barrier: does NOT drain vmcnt (global->VGPR prefetches
// stay in flight). All inter-wave data moves through LDS => lgkmcnt(0) suffices.
#define WAVE_BARRIER() do {                                          \
    asm volatile("s_waitcnt lgkmcnt(0)" ::: "memory");               \
    __builtin_amdgcn_s_barrier();                                    \
    asm volatile("" ::: "memory");                                   \
} while (0)

#define ISSUE_FENCE() asm volatile("" ::: "memory")

// ---- DPP 16-lane reduces on the VALU (not the DS pipe) ----
template <int CTRL>
__device__ __forceinline__ float dpp_add(float x) {
    int y = __builtin_amdgcn_update_dpp(0, __float_as_int(x), CTRL, 0xF, 0xF, true);
    return x + __int_as_float(y);
}
template <int CTRL>
__device__ __forceinline__ float dpp_max(float x) {
    int y = __builtin_amdgcn_update_dpp(0, __float_as_int(x), CTRL, 0xF, 0xF, true);
    return fmaxf(x, __int_as_float(y));
}
__device__ __forceinline__ float row16_sum(float x) {
    x = dpp_add<0xB1>(x);   // quad_perm xor1
    x = dpp_add<0x4E>(x);   // quad_perm xor2
    x = dpp_add<0x124>(x);  // row_ror:4
    x = dpp_add<0x128>(x);  // row_ror:8
    return x;
}
__device__ __forceinline__ float row16_max(float x) {
    x = dpp_max<0xB1>(x);
    x = dpp_max<0x4E>(x);
    x = dpp_max<0x124>(x);
    x = dpp_max<0x128>(x);
    return x;
}

// ---- prep: W1 -> fp16 MFMA-B fragment order (hi only) ----
//   flat = ((kt*16 + nt)*64 + lane)*8 + j ; element = W1[kt*32+(lane>>4)*8+j][nt*16+(lane&15)]
__global__ __launch_bounds__(256) void prep_w(const float* __restrict__ W1,
                                              _Float16* __restrict__ whi) {
    int idx = blockIdx.x * 256 + threadIdx.x;
    int j    = idx & 7;
    int lane = (idx >> 3) & 63;
    int nt   = (idx >> 9) & 15;
    int kt   = idx >> 13;
    int k = kt * 32 + ((lane >> 4) & 3) * 8 + j;
    int n = nt * 16 + (lane & 15);
    whi[idx] = (_Float16)W1[k * FF + n];
}

// ---- fused kernel: cross-slice pipeline round ----
// 512 blocks x 3 S-slices (2 blocks/CU, all resident at t=0). Double-buffered
// A (2x32 KiB). Next slice's A-loads issued AFTER the GEMM's last B load
// (issuing earlier would make every in-order vmcnt B-wait cascade-drain the
// slow HBM loads) and complete under fold+softmax+wsum => 2 of 3 stage waits
// hidden, HBM streams continuously instead of in bursts. B pipeline depth 3
// (~240 cyc cover >= L2 latency). Math identical to R7 (absmax 0.015625).
__global__ __launch_bounds__(512, 4) void ida_mfma(
    const float* __restrict__ features,
    const float* __restrict__ src_locs,
    const float* __restrict__ tar_locs,
    const _Float16* __restrict__ whi,
    const float* __restrict__ b1,
    const float* __restrict__ W2,
    const float* __restrict__ b2,
    float* __restrict__ out)
{
    __shared__ _Float16 Ahi[2][16384];   // 64 KiB: double-buffered 64x256 fp16 A
    __shared__ float SP[8 * LL];         // layer-2 partials [wave][station] (2 KiB)

    const int t    = threadIdx.x;
    const int w    = t >> 6;          // wave 0..7 -> owns cols 32w..32w+31
    const int lane = t & 63;
    const int quad = lane >> 4;
    const int l16  = lane & 15;
    const int g    = blockIdx.x;

    // ---- loop-invariant weight fragments ----
    float b1v[2], w2v[2];
    #pragma unroll
    for (int ntl = 0; ntl < 2; ++ntl) {
        int n = (w * 2 + ntl) * 16 + l16;
        b1v[ntl] = b1[n];
        w2v[ntl] = W2[n];
    }
    ISSUE_FENCE();

    // ---- prologue: issue A raw loads for slice 0 ----
    float4 araw[8];
    {
        const float* Xg0 = features + (size_t)(g * NSLICE) * (LL * FF);
        #pragma unroll
        for (int it = 0; it < 4; ++it) {
            const float4* p = (const float4*)(Xg0 + (it * 16 + l16) * FF + w * 32 + quad * 8);
            araw[2 * it + 0] = p[0];
            araw[2 * it + 1] = p[1];
        }
    }
    ISSUE_FENCE();

    #pragma unroll
    for (int i = 0; i < NSLICE; ++i) {
        const int bs = g * NSLICE + i;
        const int b  = bs / SS;
        _Float16* Abuf = &Ahi[i & 1][0];
        const float* Xg = features + (size_t)bs * (LL * FF);

        // ---- per-slice misc loads (tiny, L2-hot; consumed at softmax) ----
        float sx = src_locs[(b * LL + lane) * 2 + 0];
        float sy = src_locs[(b * LL + lane) * 2 + 1];
        float tx = tar_locs[b * 2 + 0];
        float ty = tar_locs[b * 2 + 1];
        float b2v = b2[0];
        ISSUE_FENCE();

        // ---- stage A (waits araw; misc stays in flight) ----
        // element (row r, col c) at Abuf[(G*64 + lane)*8 + j]:
        //   row = (G>>3)*16 + l16, col = (G&7)*32 + quad*8 + j
        #pragma unroll
        for (int it = 0; it < 4; ++it) {
            int G = it * 8 + w;
            float4 x0 = araw[2 * it + 0], x1 = araw[2 * it + 1];
            float xs[8] = {x0.x, x0.y, x0.z, x0.w, x1.x, x1.y, x1.z, x1.w};
            half8 hi;
            #pragma unroll
            for (int j = 0; j < 8; ++j) hi[j] = (_Float16)xs[j];
            *((half8*)&Abuf[(G * 64 + lane) * 8]) = hi;
        }

        // ---- B chunks 0,1 preload (depth-3 pipeline); in flight across barrier ----
        half8 bq[3][2];
        #pragma unroll
        for (int c = 0; c < 2; ++c)
            #pragma unroll
            for (int ntl = 0; ntl < 2; ++ntl)
                bq[c][ntl] = *((const half8*)(whi + ((size_t)(c * 16 + (w * 2 + ntl)) * 64 + lane) * 8));
        ISSUE_FENCE();

        WAVE_BARRIER();   // BAR_A: A(i) published; B chunks still in flight

        floatx4 acc[4][2] = {};   // [mt][ntl] -> 32 AGPRs

        // ---- GEMM: 8 kt steps, depth-3 B pipeline, 1 MFMA per (kt,mt,ntl) ----
        #pragma unroll
        for (int kt = 0; kt < 8; ++kt) {
            if (kt < 6) {
                #pragma unroll
                for (int ntl = 0; ntl < 2; ++ntl)
                    bq[(kt + 2) % 3][ntl] = *((const half8*)(whi + ((size_t)((kt + 2) * 16 + (w * 2 + ntl)) * 64 + lane) * 8));
            }
            #pragma unroll
            for (int mt = 0; mt < 4; ++mt) {
                half8 ahi = *((half8*)&Abuf[((mt * 8 + kt) * 64 + lane) * 8]);
                #pragma unroll
                for (int ntl = 0; ntl < 2; ++ntl)
                    acc[mt][ntl] = __builtin_amdgcn_mfma_f32_16x16x32_f16(ahi, bq[kt % 3][ntl], acc[mt][ntl], 0, 0, 0);
            }
        }

        // ---- issue NEXT slice's A loads now (after all B loads -> no cascade
        //      drain); they complete under fold+softmax+wsum (~800 cyc) ----
        if (i + 1 < NSLICE) {
            const float* Xgn = features + (size_t)(bs + 1) * (LL * FF);
            #pragma unroll
            for (int it = 0; it < 4; ++it) {
                const float4* p = (const float4*)(Xgn + (it * 16 + l16) * FF + w * 32 + quad * 8);
                araw[2 * it + 0] = p[0];
                araw[2 * it + 1] = p[1];
            }
            ISSUE_FENCE();
        }

        // ---- layer-2 fold: DPP row-reduce (VALU) ----
        #pragma unroll
        for (int mt = 0; mt < 4; ++mt) {
            #pragma unroll
            for (int r = 0; r < 4; ++r) {
                float p = 0.f;
                #pragma unroll
                for (int ntl = 0; ntl < 2; ++ntl) {
                    float h = fmaxf(acc[mt][ntl][r] + b1v[ntl], 0.f);
                    p = fmaf(h, w2v[ntl], p);
                }
                p = row16_sum(p);
                if (l16 == 0) SP[w * LL + mt * 16 + quad * 4 + r] = p;
            }
        }

        WAVE_BARRIER();   // BAR_SP: SP published

        // ---- redundant per-wave softmax (station = lane) ----
        float s = SP[0 * LL + lane] + SP[1 * LL + lane] + SP[2 * LL + lane] + SP[3 * LL + lane]
                + SP[4 * LL + lane] + SP[5 * LL + lane] + SP[6 * LL + lane] + SP[7 * LL + lane] + b2v;
        float score = fmaxf(s, 0.f);
        float dxv = sx - tx, dyv = sy - ty;
        float inv_d = 1.0f / sqrtf(dxv * dxv + dyv * dyv);
        float logit = score * inv_d;
        float m = row16_max(logit);
        m = fmaxf(m, __shfl_xor(m, 16));
        m = fmaxf(m, __shfl_xor(m, 32));
        float e = __expf(logit - m);
        float se = row16_sum(e);
        se += __shfl_xor(se, 16);
        se += __shfl_xor(se, 32);
        float wgt = e / se;   // weight of station `lane`, valid in all lanes

        // ---- weighted sum: Abuf read along staging pattern (conflict-free) +
        //      DPP row-reduce over l16; lane l16==0 stores 8 cols direct ----
        float o8[8] = {0.f, 0.f, 0.f, 0.f, 0.f, 0.f, 0.f, 0.f};
        #pragma unroll
        for (int it = 0; it < 4; ++it) {
            float wr = __shfl(wgt, it * 16 + l16);
            half8 hv = *((half8*)&Abuf[((it * 8 + w) * 64 + lane) * 8]);
            #pragma unroll
            for (int j = 0; j < 8; ++j)
                o8[j] = fmaf((float)hv[j], wr, o8[j]);
        }
        #pragma unroll
        for (int j = 0; j < 8; ++j)
            o8[j] = row16_sum(o8[j]);
        if (l16 == 0) {
            float* op = out + (size_t)bs * FF + w * 32 + quad * 8;
            float4 s0 = {o8[0], o8[1], o8[2], o8[3]};
            float4 s1 = {o8[4], o8[5], o8[6], o8[7]};
            *((float4*)op) = s0;
            *((float4*)(op + 4)) = s1;
        }
        // next iteration's stage writes the OTHER A buffer; BAR_A(i+1) orders
        // it against this slice's reads. SP rewrite is fenced by BAR_A(i+1).
    }
}

extern "C" void kernel_launch(void* const* d_in, const int* in_sizes, int n_in,
                              void* d_out, int out_size, void* d_ws, size_t ws_size,
                              hipStream_t stream) {
    const float* features = (const float*)d_in[0];
    const float* src_locs = (const float*)d_in[1];
    const float* tar_locs = (const float*)d_in[2];
    const float* W1       = (const float*)d_in[3];
    const float* b1       = (const float*)d_in[4];
    const float* W2       = (const float*)d_in[5];
    const float* b2       = (const float*)d_in[6];
    float* out = (float*)d_out;

    _Float16* whi = (_Float16*)d_ws;               // 128 KiB

    prep_w<<<dim3(FF * FF / 256), dim3(256), 0, stream>>>(W1, whi);
    ida_mfma<<<dim3(NBLK), dim3(512), 0, stream>>>(
        features, src_locs, tar_locs, whi, b1, W2, b2, out);
}